// Round 25
// baseline (32.473 us; speedup 1.0000x reference)
//
#include <hip/hip_runtime.h>
#include <hip/hip_bf16.h>

typedef __attribute__((ext_vector_type(8))) short short8;
typedef __attribute__((ext_vector_type(4))) float floatx4;

#define B_ROWS 8192
#define DIM 128
#define NPAIR 4095
// rows scaled by sqrt(log2(e)) so S_mfma = S * log2(e) and exp(S) = exp2(S_mfma)
#define RSCALE 1.2011224087864498f
// exp(S_ii) = e (unit-norm rows): diagonal handled as a constant in kfinalP
#define M_E_F 2.7182818284590452f

#define GLOAD_LDS16(gp, lp)                                                     \
    __builtin_amdgcn_global_load_lds(                                           \
        (const __attribute__((address_space(1))) void*)(gp),                    \
        (__attribute__((address_space(3))) void*)(lp), 16, 0, 0)

// ------------- prep: normalize rows -> bf16 (scaled), exact fp32 pair dots -------------
// 1024 blocks x 256 thr; wave W: rows 2W (lanes 0-31), 2W+1 (lanes 32-63), float4/lane.
__global__ void kprep(const float* __restrict__ X, __hip_bfloat16* __restrict__ XN,
                      float* __restrict__ pairT, float* __restrict__ out) {
    const int wid = threadIdx.x >> 6;
    const int lane = threadIdx.x & 63;
    const int j = lane & 31;
    const int W = blockIdx.x * 4 + wid;  // wave index == pair index
    const int row = 2 * W + (lane >> 5);

    const float4 v = *reinterpret_cast<const float4*>(X + row * DIM + j * 4);
    float ss = v.x * v.x + v.y * v.y + v.z * v.z + v.w * v.w;
    #pragma unroll
    for (int m = 1; m < 32; m <<= 1) ss += __shfl_xor(ss, m, 64);  // within half
    const float rn = ss > 0.f ? rsqrtf(ss) : 0.f;

    // exact pair similarity via cross-half shuffle
    float4 pv;
    pv.x = __shfl_xor(v.x, 32, 64);
    pv.y = __shfl_xor(v.y, 32, 64);
    pv.z = __shfl_xor(v.z, 32, 64);
    pv.w = __shfl_xor(v.w, 32, 64);
    float pd = v.x * pv.x + v.y * pv.y + v.z * pv.z + v.w * pv.w;
    #pragma unroll
    for (int m = 1; m < 32; m <<= 1) pd += __shfl_xor(pd, m, 64);
    const float rno = __shfl_xor(rn, 32, 64);
    if (lane == 0 && W < NPAIR) pairT[W] = pd * rn * rno;

    // bf16 write (scaled)
    const float sc = rn * RSCALE;
    __hip_bfloat162 h0 = __float22bfloat162_rn(make_float2(v.x * sc, v.y * sc));
    __hip_bfloat162 h1 = __float22bfloat162_rn(make_float2(v.z * sc, v.w * sc));
    struct B4 { __hip_bfloat162 a, b; };
    *reinterpret_cast<B4*>(XN + row * DIM + j * 4) = B4{h0, h1};

    if (W == 0 && lane == 0) out[0] = 0.f;
}

// ---- stage one 64x128 bf16 half-slab to LDS, 512-thread block (2 x 16B per lane) ----
// LDS[row][colL] = global[row][colL ^ ((row&7)<<3)] (linear dest, pre-swizzled source)
__device__ __forceinline__ void stage512(const __hip_bfloat16* __restrict__ gsrc,
                                         __hip_bfloat16* lbuf, int tid) {
    const int wid = tid >> 6;
    const int lane = tid & 63;
    #pragma unroll
    for (int it = 0; it < 2; ++it) {
        const int woff = it * 4096 + wid * 512;  // wave-uniform elem offset
        const int e = woff + lane * 8;
        const int src = (e & ~127) | ((e & 127) ^ (((e >> 7) & 7) << 3));
        GLOAD_LDS16(gsrc + src, lbuf + woff);
    }
}

// ------------- main: 8-wave block, 5-buffer 3-deep counted-vmcnt pipeline -------------
// grid (8, 64): y = row panel rb (128 rows), x = col group g (8 tiles = 16 slabs).
// 512 threads = 8 waves, 4x2 split: wr (0..3) = 32-row quarter, wc (0..1) = 32-col half.
// Prefetch depth 3: phase t waits vmcnt(6) [slab t landed; t+1..t+3 in flight],
// raw s_barrier (no drain), stage slab t+4, 8x ds_read (swizzled), 16 MFMA, 16 exp2.
// Tail: t=13 -> vmcnt(4), t=14 -> vmcnt(2), t=15 -> vmcnt(0).
// LDS 80KB: still 2 blocks/CU (160KB pool) -> depth increase is occupancy-free.
__global__ void __launch_bounds__(512) kgemm(const __hip_bfloat16* __restrict__ XN,
                                             float* __restrict__ ZP) {
    __shared__ __hip_bfloat16 Bs[5][64 * DIM];  // 80 KB, 5-deep ring

    const int tid = threadIdx.x;
    const int wid = tid >> 6;     // 0..7
    const int lane = tid & 63;
    const int lr = lane & 15;
    const int lk = lane >> 4;
    const int wr = wid >> 1;      // 0..3: 32-row quarter
    const int wc = wid & 1;       // 0..1: 32-col half
    const int rb = blockIdx.y;
    const int g = blockIdx.x;

    // A: 32 rows in registers: a[kk][m], rows rb*128 + wr*32 + m*16 + lr
    short8 a[4][2];
    const __hip_bfloat16* Abase = XN + (rb * 128 + wr * 32 + lr) * DIM + lk * 8;
    #pragma unroll
    for (int m = 0; m < 2; ++m)
        #pragma unroll
        for (int kk = 0; kk < 4; ++kk)
            a[kk][m] = *reinterpret_cast<const short8*>(Abase + m * 16 * DIM + kk * 32);

    float rp[2][4];
    #pragma unroll
    for (int m = 0; m < 2; ++m)
        #pragma unroll
        for (int r = 0; r < 4; ++r) rp[m][r] = 0.f;

    const floatx4 zero4 = {0.f, 0.f, 0.f, 0.f};

    // prologue: stage slabs 0..3 (slab s = tile g*8 + (s>>1), half s&1)
    stage512(XN + (size_t)(g * 8) * 128 * DIM, Bs[0], tid);
    stage512(XN + ((size_t)(g * 8) * 128 + 64) * DIM, Bs[1], tid);
    stage512(XN + ((size_t)(g * 8 + 1) * 128) * DIM, Bs[2], tid);
    stage512(XN + ((size_t)(g * 8 + 1) * 128 + 64) * DIM, Bs[3], tid);

    for (int t = 0; t < 16; ++t) {
        // counted wait: slab t landed; up to 3 newer slabs stay in flight
        if (t < 13)
            asm volatile("s_waitcnt vmcnt(6)" ::: "memory");
        else if (t == 13)
            asm volatile("s_waitcnt vmcnt(4)" ::: "memory");
        else if (t == 14)
            asm volatile("s_waitcnt vmcnt(2)" ::: "memory");
        else
            asm volatile("s_waitcnt vmcnt(0)" ::: "memory");
        __builtin_amdgcn_s_barrier();  // raw barrier: no drain

        if (t + 4 < 16)
            stage512(XN + ((size_t)(g * 8 + ((t + 4) >> 1)) * 128 + ((t + 4) & 1) * 64) * DIM,
                     Bs[(t + 4) % 5], tid);

        const __hip_bfloat16* Bt = Bs[t % 5];

        __builtin_amdgcn_s_setprio(1);
        short8 b[4][2];
        #pragma unroll
        for (int n = 0; n < 2; ++n) {
            const int row = wc * 32 + n * 16 + lr;
            #pragma unroll
            for (int kk = 0; kk < 4; ++kk) {
                const int col = (kk * 32 + lk * 8) ^ ((row & 7) << 3);
                b[kk][n] = *reinterpret_cast<const short8*>(&Bt[row * DIM + col]);
            }
        }

        floatx4 acc[2][2];
        #pragma unroll
        for (int m = 0; m < 2; ++m)
            #pragma unroll
            for (int n = 0; n < 2; ++n)
                acc[m][n] = __builtin_amdgcn_mfma_f32_16x16x32_bf16(a[0][m], b[0][n], zero4, 0, 0, 0);
        #pragma unroll
        for (int kk = 1; kk < 4; ++kk)
            #pragma unroll
            for (int m = 0; m < 2; ++m)
                #pragma unroll
                for (int n = 0; n < 2; ++n)
                    acc[m][n] = __builtin_amdgcn_mfma_f32_16x16x32_bf16(a[kk][m], b[kk][n], acc[m][n], 0, 0, 0);
        __builtin_amdgcn_s_setprio(0);

        // epilogue: exp2 + row accumulate (diagonal kept; constant e removed in kfinalP)
        #pragma unroll
        for (int m = 0; m < 2; ++m)
            #pragma unroll
            for (int n = 0; n < 2; ++n)
                #pragma unroll
                for (int r = 0; r < 4; ++r)
                    rp[m][r] += __builtin_amdgcn_exp2f(acc[m][n][r]);
    }

    // ---- row sums: reduce over lr, store P[row][slot] (16 slots, 64B/row) ----
    #pragma unroll
    for (int m = 0; m < 2; ++m)
        #pragma unroll
        for (int r = 0; r < 4; ++r) {
            float v = rp[m][r];
            v += __shfl_xor(v, 1, 64);
            v += __shfl_xor(v, 2, 64);
            v += __shfl_xor(v, 4, 64);
            v += __shfl_xor(v, 8, 64);
            if (lr == 0) {
                const int row = rb * 128 + wr * 32 + m * 16 + lk * 4 + r;
                ZP[row * 16 + (g * 2 + wc)] = v;
            }
        }
}

// ------------- final: Z[r] = sum_16 P[r][slot] - e (diag const); loss reduce -------------
__global__ void kfinalP(const float* __restrict__ P, const float* __restrict__ pairT,
                        float* __restrict__ out) {
    const int r = blockIdx.x * 256 + threadIdx.x;
    float s = 0.f;
    if (r < B_ROWS - 2) {
        const float4* p4 = reinterpret_cast<const float4*>(P + r * 16);
        float z = 0.f;
        #pragma unroll
        for (int i = 0; i < 4; ++i) {
            const float4 v = p4[i];
            z += v.x + v.y + v.z + v.w;
        }
        s = logf(z - M_E_F);
    }
    if (r < NPAIR) s -= 2.f * pairT[r];
    #pragma unroll
    for (int m = 1; m < 64; m <<= 1) s += __shfl_xor(s, m, 64);
    __shared__ float red[4];
    const int wid = threadIdx.x >> 6;
    const int lane = threadIdx.x & 63;
    if (lane == 0) red[wid] = s;
    __syncthreads();
    if (threadIdx.x == 0) {
        float tsum = red[0] + red[1] + red[2] + red[3];
        atomicAdd(out, tsum / (float)B_ROWS);
    }
}

extern "C" void kernel_launch(void* const* d_in, const int* in_sizes, int n_in,
                              void* d_out, int out_size, void* d_ws, size_t ws_size,
                              hipStream_t stream) {
    (void)in_sizes; (void)n_in; (void)out_size; (void)ws_size;
    const float* X = (const float*)d_in[0];
    float* out = (float*)d_out;
    char* ws = (char*)d_ws;

    float* pairT = (float*)ws;                               // 16 KB
    __hip_bfloat16* XN = (__hip_bfloat16*)(ws + 32768);      // 2 MB
    float* P = (float*)(ws + 32768 + 2097152);               // 512 KB (8192 x 16 f32)

    kprep<<<1024, 256, 0, stream>>>(X, XN, pairT, out);
    kgemm<<<dim3(8, 64), 512, 0, stream>>>(XN, P);
    kfinalP<<<32, 256, 0, stream>>>(P, pairT, out);
}

// Round 26
// 32.269 us; speedup vs baseline: 1.0063x; 1.0063x over previous
//
#include <hip/hip_runtime.h>
#include <hip/hip_bf16.h>

typedef __attribute__((ext_vector_type(8))) short short8;
typedef __attribute__((ext_vector_type(4))) float floatx4;

#define B_ROWS 8192
#define DIM 128
#define NPAIR 4095
// rows scaled by sqrt(log2(e)) so S_mfma = S * log2(e) and exp(S) = exp2(S_mfma)
#define RSCALE 1.2011224087864498f
// exp(S_ii) = e (unit-norm rows): diagonal handled as a constant in kfinalP
#define M_E_F 2.7182818284590452f

#define GLOAD_LDS16(gp, lp)                                                     \
    __builtin_amdgcn_global_load_lds(                                           \
        (const __attribute__((address_space(1))) void*)(gp),                    \
        (__attribute__((address_space(3))) void*)(lp), 16, 0, 0)

// ------------- prep: normalize rows -> bf16 (scaled), exact fp32 pair dots -------------
// 1024 blocks x 256 thr; wave W: rows 2W (lanes 0-31), 2W+1 (lanes 32-63), float4/lane.
__global__ void kprep(const float* __restrict__ X, __hip_bfloat16* __restrict__ XN,
                      float* __restrict__ pairT, float* __restrict__ out) {
    const int wid = threadIdx.x >> 6;
    const int lane = threadIdx.x & 63;
    const int j = lane & 31;
    const int W = blockIdx.x * 4 + wid;  // wave index == pair index
    const int row = 2 * W + (lane >> 5);

    const float4 v = *reinterpret_cast<const float4*>(X + row * DIM + j * 4);
    float ss = v.x * v.x + v.y * v.y + v.z * v.z + v.w * v.w;
    #pragma unroll
    for (int m = 1; m < 32; m <<= 1) ss += __shfl_xor(ss, m, 64);  // within half
    const float rn = ss > 0.f ? rsqrtf(ss) : 0.f;

    // exact pair similarity via cross-half shuffle
    float4 pv;
    pv.x = __shfl_xor(v.x, 32, 64);
    pv.y = __shfl_xor(v.y, 32, 64);
    pv.z = __shfl_xor(v.z, 32, 64);
    pv.w = __shfl_xor(v.w, 32, 64);
    float pd = v.x * pv.x + v.y * pv.y + v.z * pv.z + v.w * pv.w;
    #pragma unroll
    for (int m = 1; m < 32; m <<= 1) pd += __shfl_xor(pd, m, 64);
    const float rno = __shfl_xor(rn, 32, 64);
    if (lane == 0 && W < NPAIR) pairT[W] = pd * rn * rno;

    // bf16 write (scaled)
    const float sc = rn * RSCALE;
    __hip_bfloat162 h0 = __float22bfloat162_rn(make_float2(v.x * sc, v.y * sc));
    __hip_bfloat162 h1 = __float22bfloat162_rn(make_float2(v.z * sc, v.w * sc));
    struct B4 { __hip_bfloat162 a, b; };
    *reinterpret_cast<B4*>(XN + row * DIM + j * 4) = B4{h0, h1};

    if (W == 0 && lane == 0) out[0] = 0.f;
}

// ---- stage one 64x128 bf16 half-slab to LDS, 512-thread block (2 x 16B per lane) ----
// LDS[row][colL] = global[row][colL ^ ((row&7)<<3)] (linear dest, pre-swizzled source)
__device__ __forceinline__ void stage512(const __hip_bfloat16* __restrict__ gsrc,
                                         __hip_bfloat16* lbuf, int tid) {
    const int wid = tid >> 6;
    const int lane = tid & 63;
    #pragma unroll
    for (int it = 0; it < 2; ++it) {
        const int woff = it * 4096 + wid * 512;  // wave-uniform elem offset
        const int e = woff + lane * 8;
        const int src = (e & ~127) | ((e & 127) ^ (((e >> 7) & 7) << 3));
        GLOAD_LDS16(gsrc + src, lbuf + woff);
    }
}

// ------------- main: 8-wave block, 4-buffer 2-deep counted-vmcnt pipeline -------------
// grid (8, 64): y = row panel rb (128 rows), x = col group g (8 tiles = 16 slabs).
// 512 threads = 8 waves, 4x2 split: wr (0..3) = 32-row quarter, wc (0..1) = 32-col half.
// Prefetch depth 2: phase t waits vmcnt(4) [slab t landed; slabs t+1, t+2 in flight],
// raw s_barrier (no drain), stage slab t+3, 8x ds_read (swizzled), 16 MFMA, 16 exp2.
// Tail: t=14 -> vmcnt(2), t=15 -> vmcnt(0).
// CONVERGED FINAL: depth 1->2 gained (r23->r24), depth 3 flat (r25); 14 alternative
// structures (dtype/shape/symmetry/fusion/barrier-free/occupancy) all measured worse.
__global__ void __launch_bounds__(512) kgemm(const __hip_bfloat16* __restrict__ XN,
                                             float* __restrict__ ZP) {
    __shared__ __hip_bfloat16 Bs[4][64 * DIM];  // 64 KB, 4-deep ring

    const int tid = threadIdx.x;
    const int wid = tid >> 6;     // 0..7
    const int lane = tid & 63;
    const int lr = lane & 15;
    const int lk = lane >> 4;
    const int wr = wid >> 1;      // 0..3: 32-row quarter
    const int wc = wid & 1;       // 0..1: 32-col half
    const int rb = blockIdx.y;
    const int g = blockIdx.x;

    // A: 32 rows in registers: a[kk][m], rows rb*128 + wr*32 + m*16 + lr
    short8 a[4][2];
    const __hip_bfloat16* Abase = XN + (rb * 128 + wr * 32 + lr) * DIM + lk * 8;
    #pragma unroll
    for (int m = 0; m < 2; ++m)
        #pragma unroll
        for (int kk = 0; kk < 4; ++kk)
            a[kk][m] = *reinterpret_cast<const short8*>(Abase + m * 16 * DIM + kk * 32);

    float rp[2][4];
    #pragma unroll
    for (int m = 0; m < 2; ++m)
        #pragma unroll
        for (int r = 0; r < 4; ++r) rp[m][r] = 0.f;

    const floatx4 zero4 = {0.f, 0.f, 0.f, 0.f};

    // prologue: stage slabs 0,1,2 (slab s = tile g*8 + (s>>1), half s&1)
    stage512(XN + (size_t)(g * 8) * 128 * DIM, Bs[0], tid);
    stage512(XN + ((size_t)(g * 8) * 128 + 64) * DIM, Bs[1], tid);
    stage512(XN + ((size_t)(g * 8 + 1) * 128) * DIM, Bs[2], tid);

    for (int t = 0; t < 16; ++t) {
        // counted wait: slab t landed; up to 2 newer slabs stay in flight
        if (t < 14)
            asm volatile("s_waitcnt vmcnt(4)" ::: "memory");
        else if (t == 14)
            asm volatile("s_waitcnt vmcnt(2)" ::: "memory");
        else
            asm volatile("s_waitcnt vmcnt(0)" ::: "memory");
        __builtin_amdgcn_s_barrier();  // raw barrier: no drain

        if (t + 3 < 16)
            stage512(XN + ((size_t)(g * 8 + ((t + 3) >> 1)) * 128 + ((t + 3) & 1) * 64) * DIM,
                     Bs[(t + 3) & 3], tid);

        const __hip_bfloat16* Bt = Bs[t & 3];

        __builtin_amdgcn_s_setprio(1);
        short8 b[4][2];
        #pragma unroll
        for (int n = 0; n < 2; ++n) {
            const int row = wc * 32 + n * 16 + lr;
            #pragma unroll
            for (int kk = 0; kk < 4; ++kk) {
                const int col = (kk * 32 + lk * 8) ^ ((row & 7) << 3);
                b[kk][n] = *reinterpret_cast<const short8*>(&Bt[row * DIM + col]);
            }
        }

        floatx4 acc[2][2];
        #pragma unroll
        for (int m = 0; m < 2; ++m)
            #pragma unroll
            for (int n = 0; n < 2; ++n)
                acc[m][n] = __builtin_amdgcn_mfma_f32_16x16x32_bf16(a[0][m], b[0][n], zero4, 0, 0, 0);
        #pragma unroll
        for (int kk = 1; kk < 4; ++kk)
            #pragma unroll
            for (int m = 0; m < 2; ++m)
                #pragma unroll
                for (int n = 0; n < 2; ++n)
                    acc[m][n] = __builtin_amdgcn_mfma_f32_16x16x32_bf16(a[kk][m], b[kk][n], acc[m][n], 0, 0, 0);
        __builtin_amdgcn_s_setprio(0);

        // epilogue: exp2 + row accumulate (diagonal kept; constant e removed in kfinalP)
        #pragma unroll
        for (int m = 0; m < 2; ++m)
            #pragma unroll
            for (int n = 0; n < 2; ++n)
                #pragma unroll
                for (int r = 0; r < 4; ++r)
                    rp[m][r] += __builtin_amdgcn_exp2f(acc[m][n][r]);
    }

    // ---- row sums: reduce over lr, store P[row][slot] (16 slots, 64B/row) ----
    #pragma unroll
    for (int m = 0; m < 2; ++m)
        #pragma unroll
        for (int r = 0; r < 4; ++r) {
            float v = rp[m][r];
            v += __shfl_xor(v, 1, 64);
            v += __shfl_xor(v, 2, 64);
            v += __shfl_xor(v, 4, 64);
            v += __shfl_xor(v, 8, 64);
            if (lr == 0) {
                const int row = rb * 128 + wr * 32 + m * 16 + lk * 4 + r;
                ZP[row * 16 + (g * 2 + wc)] = v;
            }
        }
}

// ------------- final: Z[r] = sum_16 P[r][slot] - e (diag const); loss reduce -------------
__global__ void kfinalP(const float* __restrict__ P, const float* __restrict__ pairT,
                        float* __restrict__ out) {
    const int r = blockIdx.x * 256 + threadIdx.x;
    float s = 0.f;
    if (r < B_ROWS - 2) {
        const float4* p4 = reinterpret_cast<const float4*>(P + r * 16);
        float z = 0.f;
        #pragma unroll
        for (int i = 0; i < 4; ++i) {
            const float4 v = p4[i];
            z += v.x + v.y + v.z + v.w;
        }
        s = logf(z - M_E_F);
    }
    if (r < NPAIR) s -= 2.f * pairT[r];
    #pragma unroll
    for (int m = 1; m < 64; m <<= 1) s += __shfl_xor(s, m, 64);
    __shared__ float red[4];
    const int wid = threadIdx.x >> 6;
    const int lane = threadIdx.x & 63;
    if (lane == 0) red[wid] = s;
    __syncthreads();
    if (threadIdx.x == 0) {
        float tsum = red[0] + red[1] + red[2] + red[3];
        atomicAdd(out, tsum / (float)B_ROWS);
    }
}

extern "C" void kernel_launch(void* const* d_in, const int* in_sizes, int n_in,
                              void* d_out, int out_size, void* d_ws, size_t ws_size,
                              hipStream_t stream) {
    (void)in_sizes; (void)n_in; (void)out_size; (void)ws_size;
    const float* X = (const float*)d_in[0];
    float* out = (float*)d_out;
    char* ws = (char*)d_ws;

    float* pairT = (float*)ws;                               // 16 KB
    __hip_bfloat16* XN = (__hip_bfloat16*)(ws + 32768);      // 2 MB
    float* P = (float*)(ws + 32768 + 2097152);               // 512 KB (8192 x 16 f32)

    kprep<<<1024, 256, 0, stream>>>(X, XN, pairT, out);
    kgemm<<<dim3(8, 64), 512, 0, stream>>>(XN, P);
    kfinalP<<<32, 256, 0, stream>>>(P, pairT, out);
}